// Round 1
// baseline (3593.553 us; speedup 1.0000x reference)
//
#include <hip/hip_runtime.h>
#include <math.h>

#define N_OP_   200000
#define N_MACH_ 1000
#define N_JOB_  20000
#define E_OM_   1000000
#define E_JO_   200000
#define N_PAIRS_ 500000

#define CDIV(a,b) (((a)+(b)-1)/(b))

// ---------------- encode: out[:, :16]=sin(xW), out[:,16:32]=cos(xW); row stride 64 ----------------
template<int DIN>
__global__ __launch_bounds__(256) void encode_kernel(const float* __restrict__ x,
    const float* __restrict__ W, float* __restrict__ out, int N){
  __shared__ float sW[DIN*16];
  if (threadIdx.x < DIN*16) sW[threadIdx.x] = W[threadIdx.x];
  __syncthreads();
  int i = blockIdx.x*blockDim.x + threadIdx.x;
  if (i >= N) return;
  float xv[DIN];
#pragma unroll
  for (int k=0;k<DIN;k++) xv[k] = x[i*DIN+k];
#pragma unroll
  for (int j=0;j<16;j++){
    float h = 0.f;
#pragma unroll
    for (int k=0;k<DIN;k++) h = fmaf(xv[k], sW[k*16+j], h);
    float s, c;
    sincosf(h, &s, &c);
    out[(size_t)i*64 + j]      = s;
    out[(size_t)i*64 + 16 + j] = c;
  }
}

// ---------------- CSR build ----------------
__global__ void hist_kernel(const int* __restrict__ dstv, int E, int* __restrict__ cnt){
  int i = blockIdx.x*blockDim.x + threadIdx.x;
  int stride = gridDim.x*blockDim.x;
  for (; i<E; i+=stride) atomicAdd(&cnt[dstv[i]], 1);
}

__global__ void scan_block_sums(const int* __restrict__ cnt, int N, int* __restrict__ partials){
  __shared__ int red[256];
  int base = blockIdx.x*1024;
  int s = 0;
#pragma unroll
  for (int j=0;j<4;j++){ int i = base + threadIdx.x + j*256; if (i<N) s += cnt[i]; }
  red[threadIdx.x] = s; __syncthreads();
  for (int st=128; st>0; st>>=1){ if (threadIdx.x<st) red[threadIdx.x]+=red[threadIdx.x+st]; __syncthreads(); }
  if (threadIdx.x==0) partials[blockIdx.x] = red[0];
}

__global__ void scan_partials(int* __restrict__ partials, int NB, int* __restrict__ offN){
  // single block of 256; NB <= 256
  __shared__ int buf[256];
  int v = (threadIdx.x < NB) ? partials[threadIdx.x] : 0;
  buf[threadIdx.x] = v; __syncthreads();
  int acc = v;
  for (int st=1; st<256; st<<=1){
    int t = (threadIdx.x >= st) ? buf[threadIdx.x-st] : 0;
    __syncthreads();
    acc += t; buf[threadIdx.x] = acc;
    __syncthreads();
  }
  if (threadIdx.x < NB) partials[threadIdx.x] = acc - v;  // exclusive
  if (threadIdx.x == NB-1) offN[0] = acc;                 // total
}

__global__ void scan_write_offsets(const int* __restrict__ cnt, int N,
    const int* __restrict__ partials, int* __restrict__ off){
  __shared__ int buf[256];
  int base = blockIdx.x*1024;
  int v[4]; int s = 0;
#pragma unroll
  for (int j=0;j<4;j++){ int i = base + threadIdx.x*4 + j; v[j] = (i<N)?cnt[i]:0; s += v[j]; }
  buf[threadIdx.x] = s; __syncthreads();
  int acc = s;
  for (int st=1; st<256; st<<=1){
    int t = (threadIdx.x >= st) ? buf[threadIdx.x-st] : 0;
    __syncthreads();
    acc += t; buf[threadIdx.x] = acc;
    __syncthreads();
  }
  int ex = partials[blockIdx.x] + acc - s;
#pragma unroll
  for (int j=0;j<4;j++){ int i = base + threadIdx.x*4 + j; if (i<N) off[i] = ex; ex += v[j]; }
}

__global__ void fill_kernel(const int* __restrict__ srcv, const int* __restrict__ dstv, int E,
    int* __restrict__ cursor, int* __restrict__ elist){
  int i = blockIdx.x*blockDim.x + threadIdx.x;
  int stride = gridDim.x*blockDim.x;
  for (; i<E; i+=stride){
    int d = dstv[i];
    int p = atomicAdd(&cursor[d], 1);
    elist[p] = srcv[i];
  }
}

// ---------------- aggregation (CSR gather, no atomics) ----------------
__global__ __launch_bounds__(256) void agg_wave_kernel(const int* __restrict__ off,
    const int* __restrict__ srcs, const float* __restrict__ feat,
    float* __restrict__ outp, int Ndst, int D){
  int gw   = (blockIdx.x*256 + threadIdx.x) >> 6;
  int lane = threadIdx.x & 63;
  if (gw >= Ndst) return;
  int s = off[gw], e = off[gw+1];
  if (lane >= D) return;
  float acc = 0.f;
  for (int i=s;i<e;i++){
    int r = srcs[i];
    acc += feat[(size_t)r*64 + lane];
  }
  outp[(size_t)gw*64 + lane] = acc;
}

__global__ __launch_bounds__(256) void agg_block_kernel(const int* __restrict__ off,
    const int* __restrict__ srcs, const float* __restrict__ feat,
    float* __restrict__ outp, int Ndst, int D){
  __shared__ float red[4][64];
  int m = blockIdx.x;
  if (m >= Ndst) return;
  int g = threadIdx.x >> 6, lane = threadIdx.x & 63;
  int s = off[m], e = off[m+1];
  float acc = 0.f;
  if (lane < D){
    for (int i=s+g; i<e; i+=4) acc += feat[(size_t)srcs[i]*64 + lane];
  }
  red[g][lane] = acc;
  __syncthreads();
  if (g==0 && lane<D)
    outp[(size_t)m*64+lane] = red[0][lane]+red[1][lane]+red[2][lane]+red[3][lane];
}

// ---------------- GIN part A: h1 = ((1+eps)x + agg) @ W1 + b1 (in-place over agg), + BN stats ----------------
template<int DIN>
__global__ __launch_bounds__(256) void partA_kernel(
    const float* __restrict__ x, float* __restrict__ h,
    const float* __restrict__ W1, const float* __restrict__ b1,
    const float* __restrict__ epsp, int epsidx,
    int N, float* __restrict__ ssum, float* __restrict__ ssq){
  __shared__ __align__(16) float zbuf[4][DIN];
  __shared__ float red[4][64];
  const int lane = threadIdx.x & 63;
  const int w = threadIdx.x >> 6;
  float wcol[DIN];
#pragma unroll
  for (int k=0;k<DIN;k++) wcol[k] = W1[k*64 + lane];
  const float bias = b1[lane];
  const float e1 = 1.0f + epsp[epsidx];
  float psum = 0.f, psq = 0.f;
  for (int base = blockIdx.x*4; base < N; base += gridDim.x*4){
    int row = base + w;
    bool act = row < N;
    __syncthreads();
    if (act && lane < DIN)
      zbuf[w][lane] = e1*x[(size_t)row*64+lane] + h[(size_t)row*64+lane];
    __syncthreads();
    if (act){
      float acc = bias;
      const float4* Z4 = (const float4*)zbuf[w];
#pragma unroll
      for (int k4=0;k4<DIN/4;k4++){
        float4 z = Z4[k4];
        acc += z.x*wcol[4*k4+0] + z.y*wcol[4*k4+1] + z.z*wcol[4*k4+2] + z.w*wcol[4*k4+3];
      }
      h[(size_t)row*64+lane] = acc;
      psum += acc; psq += acc*acc;
    }
  }
  red[w][lane] = psum; __syncthreads();
  if (w==0) atomicAdd(&ssum[lane], red[0][lane]+red[1][lane]+red[2][lane]+red[3][lane]);
  __syncthreads();
  red[w][lane] = psq; __syncthreads();
  if (w==0) atomicAdd(&ssq[lane], red[0][lane]+red[1][lane]+red[2][lane]+red[3][lane]);
}

// ---------------- BN finalize (4 GINs of a layer at once) ----------------
__global__ void bn_fin4_kernel(const float* __restrict__ stats,
    const float* __restrict__ g1, const float* __restrict__ be1, int l,
    float* __restrict__ scsh){
  int t = threadIdx.x;
  if (t >= 256) return;
  int gi = t>>6, c = t&63;
  float N = (gi==0) ? 1000.f : (gi==3) ? 20000.f : 200000.f;
  float invN = 1.f/N;
  float s = stats[gi*128 + c];
  float q = stats[gi*128 + 64 + c];
  float m = s*invN;
  float var = q*invN - m*m;
  float inv = rsqrtf(var + 1e-5f);
  float gg = g1[((size_t)l*4+gi)*64 + c];
  float bb = be1[((size_t)l*4+gi)*64 + c];
  float sc = gg*inv;
  scsh[gi*128 + c]      = sc;
  scsh[gi*128 + 64 + c] = bb - m*sc;
}

__global__ void bn_fin_kernel(const float* __restrict__ ssum, const float* __restrict__ ssq,
    const float* __restrict__ g, const float* __restrict__ be, float invN, int C,
    float* __restrict__ sc, float* __restrict__ sh){
  int c = threadIdx.x;
  if (c >= C) return;
  float m = ssum[c]*invN;
  float var = ssq[c]*invN - m*m;
  float inv = rsqrtf(var + 1e-5f);
  float s = g[c]*inv;
  sc[c] = s; sh[c] = be[c] - m*s;
}

// ---------------- GIN part B ----------------
template<bool RESID>
__global__ __launch_bounds__(256) void partB_single_kernel(
    float* __restrict__ h1, const float* __restrict__ xold,
    const float* __restrict__ W2, const float* __restrict__ b2,
    const float* __restrict__ sc, const float* __restrict__ sh, int N){
  __shared__ __align__(16) float zbuf[4][64];
  const int lane = threadIdx.x & 63, w = threadIdx.x >> 6;
  float wcol[64];
#pragma unroll
  for (int k=0;k<64;k++) wcol[k] = W2[k*64+lane];
  const float bias = b2[lane];
  const float msc = sc[lane], msh = sh[lane];
  for (int base = blockIdx.x*4; base < N; base += gridDim.x*4){
    int row = base + w; bool act = row < N;
    __syncthreads();
    if (act){
      float v = msc*h1[(size_t)row*64+lane] + msh;
      zbuf[w][lane] = v>0.f ? v : 0.f;
    }
    __syncthreads();
    if (act){
      float acc = bias;
      const float4* Z4 = (const float4*)zbuf[w];
#pragma unroll
      for (int k4=0;k4<16;k4++){
        float4 z = Z4[k4];
        acc += z.x*wcol[4*k4+0] + z.y*wcol[4*k4+1] + z.z*wcol[4*k4+2] + z.w*wcol[4*k4+3];
      }
      if (RESID) acc += xold[(size_t)row*64+lane];
      h1[(size_t)row*64+lane] = acc;
    }
  }
}

template<bool RESID>
__global__ __launch_bounds__(256) void partB_double_kernel(
    float* __restrict__ h1a, const float* __restrict__ h1b, const float* __restrict__ xold,
    const float* __restrict__ W2a, const float* __restrict__ W2b,
    const float* __restrict__ b2a, const float* __restrict__ b2b,
    const float* __restrict__ sca, const float* __restrict__ sha,
    const float* __restrict__ scb, const float* __restrict__ shb, int N){
  __shared__ __align__(16) float za[4][64];
  __shared__ __align__(16) float zb[4][64];
  const int lane = threadIdx.x & 63, w = threadIdx.x >> 6;
  float wa[64], wb[64];
#pragma unroll
  for (int k=0;k<64;k++){ wa[k] = W2a[k*64+lane]; wb[k] = W2b[k*64+lane]; }
  const float bias = b2a[lane] + b2b[lane];
  const float mca = sca[lane], mha = sha[lane], mcb = scb[lane], mhb = shb[lane];
  for (int base = blockIdx.x*4; base < N; base += gridDim.x*4){
    int row = base + w; bool act = row < N;
    __syncthreads();
    if (act){
      float va = mca*h1a[(size_t)row*64+lane] + mha;
      float vb = mcb*h1b[(size_t)row*64+lane] + mhb;
      za[w][lane] = va>0.f ? va : 0.f;
      zb[w][lane] = vb>0.f ? vb : 0.f;
    }
    __syncthreads();
    if (act){
      float acc = bias;
      const float4* A4 = (const float4*)za[w];
      const float4* B4 = (const float4*)zb[w];
#pragma unroll
      for (int k4=0;k4<16;k4++){
        float4 a = A4[k4], b = B4[k4];
        acc += a.x*wa[4*k4+0] + a.y*wa[4*k4+1] + a.z*wa[4*k4+2] + a.w*wa[4*k4+3];
        acc += b.x*wb[4*k4+0] + b.y*wb[4*k4+1] + b.z*wb[4*k4+2] + b.w*wb[4*k4+3];
      }
      if (RESID) acc += xold[(size_t)row*64+lane];
      h1a[(size_t)row*64+lane] = acc;
    }
  }
}

// ---------------- final stage ----------------
__global__ __launch_bounds__(256) void final_pass1_kernel(
    const float* __restrict__ Xop, const float* __restrict__ Xma, const float* __restrict__ Xjb,
    const int* __restrict__ vpo, const int* __restrict__ vpm, const int* __restrict__ vpj,
    const float* __restrict__ Ws1, const float* __restrict__ bs1,
    int P, float* __restrict__ ssum, float* __restrict__ ssq){
  __shared__ __align__(16) float zbuf[4][192];
  __shared__ float red[4][64];
  const int lane = threadIdx.x & 63, w = threadIdx.x >> 6;
  float wcol[192];
#pragma unroll
  for (int k=0;k<192;k++) wcol[k] = Ws1[k*64+lane];
  const float bias = bs1[lane];
  float psum = 0.f, psq = 0.f;
  for (int base = blockIdx.x*4; base < P; base += gridDim.x*4){
    int row = base + w; bool act = row < P;
    __syncthreads();
    if (act){
      zbuf[w][lane]      = Xop[(size_t)vpo[row]*64+lane];
      zbuf[w][64+lane]   = Xma[(size_t)vpm[row]*64+lane];
      zbuf[w][128+lane]  = Xjb[(size_t)vpj[row]*64+lane];
    }
    __syncthreads();
    if (act){
      float acc = bias;
      const float4* Z4 = (const float4*)zbuf[w];
#pragma unroll
      for (int k4=0;k4<48;k4++){
        float4 z = Z4[k4];
        acc += z.x*wcol[4*k4+0] + z.y*wcol[4*k4+1] + z.z*wcol[4*k4+2] + z.w*wcol[4*k4+3];
      }
      psum += acc; psq += acc*acc;
    }
  }
  red[w][lane] = psum; __syncthreads();
  if (w==0) atomicAdd(&ssum[lane], red[0][lane]+red[1][lane]+red[2][lane]+red[3][lane]);
  __syncthreads();
  red[w][lane] = psq; __syncthreads();
  if (w==0) atomicAdd(&ssq[lane], red[0][lane]+red[1][lane]+red[2][lane]+red[3][lane]);
}

__global__ __launch_bounds__(256) void final_pass2_kernel(
    const float* __restrict__ Xop, const float* __restrict__ Xma, const float* __restrict__ Xjb,
    const int* __restrict__ vpo, const int* __restrict__ vpm, const int* __restrict__ vpj,
    const float* __restrict__ Ws1, const float* __restrict__ bs1,
    const float* __restrict__ sc1, const float* __restrict__ sh1,
    const float* __restrict__ Ws2, const float* __restrict__ bs2,
    float* __restrict__ s2out, int P,
    float* __restrict__ ssum2, float* __restrict__ ssq2){
  __shared__ __align__(16) float zbuf[4][192];
  __shared__ float a1[4][64];
  __shared__ float w2s[64*32];
  __shared__ float red[4][32];
  const int lane = threadIdx.x & 63, w = threadIdx.x >> 6;
  for (int i=threadIdx.x; i<64*32; i+=256) w2s[i] = Ws2[i];
  float wcol[192];
#pragma unroll
  for (int k=0;k<192;k++) wcol[k] = Ws1[k*64+lane];
  const float bias = bs1[lane], c1 = sc1[lane], s1v = sh1[lane];
  const float b2v = (lane<32) ? bs2[lane] : 0.f;
  float psum = 0.f, psq = 0.f;
  __syncthreads();
  for (int base = blockIdx.x*4; base < P; base += gridDim.x*4){
    int row = base + w; bool act = row < P;
    __syncthreads();
    if (act){
      zbuf[w][lane]      = Xop[(size_t)vpo[row]*64+lane];
      zbuf[w][64+lane]   = Xma[(size_t)vpm[row]*64+lane];
      zbuf[w][128+lane]  = Xjb[(size_t)vpj[row]*64+lane];
    }
    __syncthreads();
    if (act){
      float acc = bias;
      const float4* Z4 = (const float4*)zbuf[w];
#pragma unroll
      for (int k4=0;k4<48;k4++){
        float4 z = Z4[k4];
        acc += z.x*wcol[4*k4+0] + z.y*wcol[4*k4+1] + z.z*wcol[4*k4+2] + z.w*wcol[4*k4+3];
      }
      float a = c1*acc + s1v;
      a1[w][lane] = a>0.f ? a : 0.f;
    }
    __syncthreads();
    if (act && lane<32){
      float acc2 = b2v;
#pragma unroll
      for (int k=0;k<64;k++) acc2 += a1[w][k]*w2s[k*32+lane];
      s2out[(size_t)row*32+lane] = acc2;
      psum += acc2; psq += acc2*acc2;
    }
  }
  if (lane<32) red[w][lane] = psum;
  __syncthreads();
  if (w==0 && lane<32) atomicAdd(&ssum2[lane], red[0][lane]+red[1][lane]+red[2][lane]+red[3][lane]);
  __syncthreads();
  if (lane<32) red[w][lane] = psq;
  __syncthreads();
  if (w==0 && lane<32) atomicAdd(&ssq2[lane], red[0][lane]+red[1][lane]+red[2][lane]+red[3][lane]);
}

__global__ __launch_bounds__(256) void final_pass3_kernel(
    const float* __restrict__ s2, const float* __restrict__ Ws3, const float* __restrict__ bs3,
    const float* __restrict__ sc2, const float* __restrict__ sh2,
    float* __restrict__ outp, int P){
  __shared__ float w3[32], c2[32], h2[32];
  __shared__ float b3;
  if (threadIdx.x < 32){ w3[threadIdx.x]=Ws3[threadIdx.x]; c2[threadIdx.x]=sc2[threadIdx.x]; h2[threadIdx.x]=sh2[threadIdx.x]; }
  if (threadIdx.x == 0) b3 = bs3[0];
  __syncthreads();
  int r = blockIdx.x*blockDim.x + threadIdx.x;
  if (r >= P) return;
  float acc = b3;
  const float4* S4 = (const float4*)(s2 + (size_t)r*32);
#pragma unroll
  for (int k4=0;k4<8;k4++){
    float4 v = S4[k4];
    float a;
    a = c2[4*k4+0]*v.x + h2[4*k4+0]; acc += (a>0.f?a:0.f)*w3[4*k4+0];
    a = c2[4*k4+1]*v.y + h2[4*k4+1]; acc += (a>0.f?a:0.f)*w3[4*k4+1];
    a = c2[4*k4+2]*v.z + h2[4*k4+2]; acc += (a>0.f?a:0.f)*w3[4*k4+2];
    a = c2[4*k4+3]*v.w + h2[4*k4+3]; acc += (a>0.f?a:0.f)*w3[4*k4+3];
  }
  outp[r] = acc;
}

// ---------------- host ----------------
extern "C" void kernel_launch(void* const* d_in, const int* in_sizes, int n_in,
                              void* d_out, int out_size, void* d_ws, size_t ws_size,
                              hipStream_t stream){
  (void)in_sizes; (void)n_in; (void)out_size; (void)ws_size;
  const float* x_op   = (const float*)d_in[0];
  const float* x_ma   = (const float*)d_in[1];
  const float* x_jb   = (const float*)d_in[2];
  const float* Wenc_op= (const float*)d_in[3];
  const float* Wenc_ma= (const float*)d_in[4];
  const float* Wenc_jb= (const float*)d_in[5];
  const float* gW1_l0 = (const float*)d_in[6];
  const float* gW1_l12= (const float*)d_in[7];
  const float* gb1    = (const float*)d_in[8];
  const float* gg1    = (const float*)d_in[9];
  const float* gbe1   = (const float*)d_in[10];
  const float* gW2    = (const float*)d_in[11];
  const float* gb2    = (const float*)d_in[12];
  const float* geps   = (const float*)d_in[13];
  const float* Ws1    = (const float*)d_in[14];
  const float* bs1    = (const float*)d_in[15];
  const float* gs1    = (const float*)d_in[16];
  const float* bes1   = (const float*)d_in[17];
  const float* Ws2    = (const float*)d_in[18];
  const float* bs2    = (const float*)d_in[19];
  const float* gs2    = (const float*)d_in[20];
  const float* bes2   = (const float*)d_in[21];
  const float* Ws3    = (const float*)d_in[22];
  const float* bs3    = (const float*)d_in[23];
  const int* eom_s = (const int*)d_in[24];
  const int* eom_d = (const int*)d_in[25];
  const int* emo_s = (const int*)d_in[26];
  const int* emo_d = (const int*)d_in[27];
  const int* ejo_s = (const int*)d_in[28];
  const int* ejo_d = (const int*)d_in[29];
  const int* eoj_s = (const int*)d_in[30];
  const int* eoj_d = (const int*)d_in[31];
  const int* vpo = (const int*)d_in[32];
  const int* vpm = (const int*)d_in[33];
  const int* vpj = (const int*)d_in[34];
  float* outp = (float*)d_out;

  char* wsp = (char*)d_ws;
  auto alloc = [&](size_t bytes)->void*{
    void* p = (void*)wsp;
    wsp += (bytes + 255) & ~(size_t)255;
    return p;
  };
  float* P0 = (float*)alloc((size_t)N_OP_*64*4);
  float* P1 = (float*)alloc((size_t)N_OP_*64*4);
  float* P2 = (float*)alloc((size_t)N_OP_*64*4);
  float* J0 = (float*)alloc((size_t)N_JOB_*64*4);
  float* J1 = (float*)alloc((size_t)N_JOB_*64*4);
  float* M0 = (float*)alloc((size_t)N_MACH_*64*4);
  float* M1 = (float*)alloc((size_t)N_MACH_*64*4);
  float* S2 = (float*)alloc((size_t)N_PAIRS_*32*4);
  int* off_om = (int*)alloc((size_t)(N_MACH_+1)*4);
  int* el_om  = (int*)alloc((size_t)E_OM_*4);
  int* off_mo = (int*)alloc((size_t)(N_OP_+1)*4);
  int* el_mo  = (int*)alloc((size_t)E_OM_*4);
  int* off_jo = (int*)alloc((size_t)(N_OP_+1)*4);
  int* el_jo  = (int*)alloc((size_t)E_JO_*4);
  int* off_oj = (int*)alloc((size_t)(N_JOB_+1)*4);
  int* el_oj  = (int*)alloc((size_t)E_JO_*4);
  int* cursor = (int*)alloc((size_t)(N_OP_+1)*4);
  int* partials = (int*)alloc(1024*4);
  float* lstats = (float*)alloc(512*4);
  float* lscsh  = (float*)alloc(512*4);
  float* fstats = (float*)alloc(512*4);

  // -------- encode --------
  encode_kernel<8><<<CDIV(N_OP_,256),256,0,stream>>>(x_op, Wenc_op, P0, N_OP_);
  encode_kernel<4><<<CDIV(N_MACH_,256),256,0,stream>>>(x_ma, Wenc_ma, M0, N_MACH_);
  encode_kernel<4><<<CDIV(N_JOB_,256),256,0,stream>>>(x_jb, Wenc_jb, J0, N_JOB_);

  // -------- CSR builds (once; reused by all 3 layers) --------
  auto buildCSR = [&](const int* dstv, const int* srcv, int E, int Ndst, int* off, int* elist){
    hipMemsetAsync(cursor, 0, (size_t)Ndst*4, stream);
    int g = CDIV(E,256); if (g>4096) g=4096;
    hist_kernel<<<g,256,0,stream>>>(dstv, E, cursor);
    int NB = CDIV(Ndst,1024);
    scan_block_sums<<<NB,256,0,stream>>>(cursor, Ndst, partials);
    scan_partials<<<1,256,0,stream>>>(partials, NB, off+Ndst);
    scan_write_offsets<<<NB,256,0,stream>>>(cursor, Ndst, partials, off);
    hipMemcpyAsync(cursor, off, (size_t)Ndst*4, hipMemcpyDeviceToDevice, stream);
    fill_kernel<<<g,256,0,stream>>>(srcv, dstv, E, cursor, elist);
  };
  buildCSR(eom_d, eom_s, E_OM_, N_MACH_, off_om, el_om);
  buildCSR(emo_d, emo_s, E_OM_, N_OP_,   off_mo, el_mo);
  buildCSR(ejo_d, ejo_s, E_JO_, N_OP_,   off_jo, el_jo);
  buildCSR(eoj_d, eoj_s, E_JO_, N_JOB_,  off_oj, el_oj);

  float *Xop=P0, *Aop=P1, *Bop=P2;
  float *Xjb=J0, *Ajb=J1;
  float *Xma=M0, *Ama=M1;

  for (int l=0; l<3; l++){
    int Din = (l==0) ? 32 : 64;
    // aggregations (gather, write every dst row)
    agg_block_kernel<<<N_MACH_,256,0,stream>>>(off_om, el_om, Xop, Ama, N_MACH_, Din);
    agg_wave_kernel<<<CDIV(N_OP_,4),256,0,stream>>>(off_mo, el_mo, Xma, Aop, N_OP_, Din);
    agg_wave_kernel<<<CDIV(N_OP_,4),256,0,stream>>>(off_jo, el_jo, Xjb, Bop, N_OP_, Din);
    agg_wave_kernel<<<CDIV(N_JOB_,4),256,0,stream>>>(off_oj, el_oj, Xop, Ajb, N_JOB_, Din);
    hipMemsetAsync(lstats, 0, 512*4, stream);
    // part A (h1 in place of agg) + BN stats
    auto launchA = [&](const float* xx, float* hh, int e, int N){
      const float* W1 = (l==0) ? gW1_l0 + (size_t)e*32*64
                               : gW1_l12 + ((size_t)(l-1)*4+e)*64*64;
      const float* b1 = gb1 + ((size_t)l*4+e)*64;
      float* ss = lstats + e*128;
      int grid = CDIV(N,4); if (grid>2048) grid=2048;
      if (l==0) partA_kernel<32><<<grid,256,0,stream>>>(xx,hh,W1,b1,geps,l*4+e,N,ss,ss+64);
      else      partA_kernel<64><<<grid,256,0,stream>>>(xx,hh,W1,b1,geps,l*4+e,N,ss,ss+64);
    };
    launchA(Xma, Ama, 0, N_MACH_);
    launchA(Xop, Aop, 1, N_OP_);
    launchA(Xop, Bop, 2, N_OP_);
    launchA(Xjb, Ajb, 3, N_JOB_);
    bn_fin4_kernel<<<1,256,0,stream>>>(lstats, gg1, gbe1, l, lscsh);
    // part B
    const float* W2m = gW2 + ((size_t)l*4+0)*64*64; const float* b2m = gb2 + ((size_t)l*4+0)*64;
    const float* W2a = gW2 + ((size_t)l*4+1)*64*64; const float* b2a = gb2 + ((size_t)l*4+1)*64;
    const float* W2b = gW2 + ((size_t)l*4+2)*64*64; const float* b2b = gb2 + ((size_t)l*4+2)*64;
    const float* W2j = gW2 + ((size_t)l*4+3)*64*64; const float* b2j = gb2 + ((size_t)l*4+3)*64;
    int gm = CDIV(N_MACH_,4);
    int go = 2048;
    int gj = CDIV(N_JOB_,4); if (gj>2048) gj=2048;
    if (l==0){
      partB_single_kernel<false><<<gm,256,0,stream>>>(Ama, Xma, W2m, b2m, lscsh+0, lscsh+64, N_MACH_);
      partB_double_kernel<false><<<go,256,0,stream>>>(Aop, Bop, Xop, W2a, W2b, b2a, b2b,
          lscsh+128, lscsh+192, lscsh+256, lscsh+320, N_OP_);
      partB_single_kernel<false><<<gj,256,0,stream>>>(Ajb, Xjb, W2j, b2j, lscsh+384, lscsh+448, N_JOB_);
    } else {
      partB_single_kernel<true><<<gm,256,0,stream>>>(Ama, Xma, W2m, b2m, lscsh+0, lscsh+64, N_MACH_);
      partB_double_kernel<true><<<go,256,0,stream>>>(Aop, Bop, Xop, W2a, W2b, b2a, b2b,
          lscsh+128, lscsh+192, lscsh+256, lscsh+320, N_OP_);
      partB_single_kernel<true><<<gj,256,0,stream>>>(Ajb, Xjb, W2j, b2j, lscsh+384, lscsh+448, N_JOB_);
    }
    { float* t=Xma; Xma=Ama; Ama=t; }
    { float* t=Xop; Xop=Aop; Aop=t; }
    { float* t=Xjb; Xjb=Ajb; Ajb=t; }
  }

  // -------- final MLP over 500k gathered pairs --------
  float* fsum1 = fstats;       float* fsq1 = fstats+64;
  float* fsum2 = fstats+128;   float* fsq2 = fstats+160;
  float* sc1 = fstats+192;     float* sh1 = fstats+256;
  float* sc2 = fstats+320;     float* sh2 = fstats+352;
  hipMemsetAsync(fstats, 0, 192*4, stream);
  final_pass1_kernel<<<2048,256,0,stream>>>(Xop,Xma,Xjb,vpo,vpm,vpj,Ws1,bs1,N_PAIRS_,fsum1,fsq1);
  bn_fin_kernel<<<1,64,0,stream>>>(fsum1,fsq1,gs1,bes1, 1.f/(float)N_PAIRS_, 64, sc1, sh1);
  final_pass2_kernel<<<2048,256,0,stream>>>(Xop,Xma,Xjb,vpo,vpm,vpj,Ws1,bs1,sc1,sh1,Ws2,bs2,S2,N_PAIRS_,fsum2,fsq2);
  bn_fin_kernel<<<1,32,0,stream>>>(fsum2,fsq2,gs2,bes2, 1.f/(float)N_PAIRS_, 32, sc2, sh2);
  final_pass3_kernel<<<CDIV(N_PAIRS_,256),256,0,stream>>>(S2, Ws3, bs3, sc2, sh2, outp, N_PAIRS_);
}